// Round 6
// baseline (151.678 us; speedup 1.0000x reference)
//
#include <hip/hip_runtime.h>

// LSTM: IN=2, HID=4, OUT=2, B=8192, T=1024.
// 16 lanes per batch element, gate-minor: lane = unit*4 + gate.
//   - gate broadcast within quad: quad_perm (DPP);
//   - h gather across quads: row_ror:4/8/12 (DPP), weights permuted (j-m)&3.
// Cell state pre-scaled: d = KTC*c, KTC = -2*log2(e); gate weights
// pre-scaled by -log2(e) (g gate by -2*log2(e)).
// KEY FIX THIS ROUND: opaque register pins (asm "+v") on all loop-invariant
// weights and the x double-buffer. Prev builds allocated only 36 VGPRs and
// rematerialized weights via in-loop VMEM loads (issue ~126 cy/step vs ~60
// in source, ~200 cy/step vmcnt stalls on the recurrence chain). The empty
// asm may "modify" the value, so reloading from memory becomes illegal and
// the allocator must keep them register-resident.

#define T_LEN 1024
#define NW (T_LEN / 8)

template <int C>
__device__ __forceinline__ float dppf(float v) {
  return __builtin_bit_cast(float,
      __builtin_amdgcn_mov_dpp(__builtin_bit_cast(int, v), C, 0xf, 0xf, true));
}

#define PIN(v) asm volatile("" : "+v"(v))

__global__ __launch_bounds__(256, 2) void lstm_fused(
    const float* __restrict__ x, const float* __restrict__ w_ih,
    const float* __restrict__ w_hh, const float* __restrict__ b_ih,
    const float* __restrict__ b_hh, const float* __restrict__ w_lin,
    const float* __restrict__ b_lin, float* __restrict__ out) {
  const int tid = blockIdx.x * 256 + threadIdx.x;
  const int b = tid >> 4;        // batch element (one per 16-lane group)
  const int l = tid & 15;        // lane within group
  const int gi = l & 3;          // gate index: 0=i 1=f 2=g 3=o
  const int j = (l >> 2) & 3;    // hidden unit = quad index

  const float L2E = 1.4426950408889634f;
  const float KTC = -2.0f * L2E;  // d = KTC * c

  const int row = gi * 4 + j;     // PyTorch row = gi*4 + j
  const float sc = (gi == 2) ? (-2.0f * L2E) : (-L2E);
  float wih0 = w_ih[row * 2 + 0] * sc;
  float wih1 = w_ih[row * 2 + 1] * sc;
  float bias = (b_ih[row] + b_hh[row]) * sc;
  // r_m (from row_ror:4m) = h_{(j-m)&3}
  const int i1 = (j + 3) & 3, i2 = (j + 2) & 3, i3 = (j + 1) & 3;
  float whh0 = w_hh[row * 4 + j] * sc;
  float whh1 = w_hh[row * 4 + i1] * sc;
  float whh2 = w_hh[row * 4 + i2] * sc;
  float whh3 = w_hh[row * 4 + i3] * sc;
  // Post-rcp uniform fma: sigmoid lanes -> val = rcp; g lane -> KTC*tanh(g).
  float PA = (gi == 2) ? (2.0f * KTC) : 1.0f;
  float PB = (gi == 2) ? (-KTC) : 0.0f;
  const int o = l & 1;
  float wl0 = w_lin[o * 4 + j];
  float wl1 = w_lin[o * 4 + i1];
  float wl2 = w_lin[o * 4 + i2];
  float wl3 = w_lin[o * 4 + i3];
  float blv = b_lin[o];
  const int sl = l >> 1;  // the step this lane stores

  // Pin every loop-invariant in a VGPR (zero instructions emitted).
  PIN(wih0); PIN(wih1); PIN(bias);
  PIN(whh0); PIN(whh1); PIN(whh2); PIN(whh3);
  PIN(PA); PIN(PB);
  PIN(wl0); PIN(wl1); PIN(wl2); PIN(wl3); PIN(blv);

  float d = 0.0f;                                   // scaled cell state
  float r0 = 0.0f, r1 = 0.0f, r2 = 0.0f, r3 = 0.0f;

  const float4* xq = (const float4*)(x + (size_t)b * (T_LEN * 2));
  float* op = out + (size_t)b * (T_LEN * 2) + l;

  float4 xa0 = xq[0], xa1 = xq[1], xa2 = xq[2], xa3 = xq[3];
  float4 xb0 = xq[4], xb1 = xq[5], xb2 = xq[6], xb3 = xq[7];

  for (int w = 0; w < NW; ++w) {
    const int wn = (w + 2 < NW) ? (w + 2) : w;  // clamped tail prefetch
    const float4* pn = xq + (size_t)wn * 4;
    float4 xc0 = pn[0], xc1 = pn[1], xc2 = pn[2], xc3 = pn[3];

    // Keep both x buffers register-resident across the window.
    PIN(xa0.x); PIN(xa0.y); PIN(xa0.z); PIN(xa0.w);
    PIN(xa1.x); PIN(xa1.y); PIN(xa1.z); PIN(xa1.w);
    PIN(xa2.x); PIN(xa2.y); PIN(xa2.z); PIN(xa2.w);
    PIN(xa3.x); PIN(xa3.y); PIN(xa3.z); PIN(xa3.w);
    PIN(xb0.x); PIN(xb0.y); PIN(xb0.z); PIN(xb0.w);
    PIN(xb1.x); PIN(xb1.y); PIN(xb1.z); PIN(xb1.w);
    PIN(xb2.x); PIN(xb2.y); PIN(xb2.z); PIN(xb2.w);
    PIN(xb3.x); PIN(xb3.y); PIN(xb3.z); PIN(xb3.w);

    float keep = 0.0f;

#define STEP(s, X0, X1)                                                    \
  do {                                                                     \
    float ax = fmaf((X1), wih1, fmaf((X0), wih0, bias));                   \
    float u = fmaf(r0, whh0, ax);                                          \
    float v = fmaf(r1, whh1, u);                                           \
    float q = fmaf(r3, whh3, r2 * whh2);                                   \
    float a = v + q;                                                       \
    float e = __builtin_amdgcn_exp2f(a);                                   \
    float rr = __builtin_amdgcn_rcpf(1.0f + e);                            \
    float val = fmaf(rr, PA, PB);                                          \
    float si = dppf<0x00>(val); /* quad lane 0 = gate i */                 \
    float sf = dppf<0x55>(val); /* quad lane 1 = gate f */                 \
    float tg = dppf<0xAA>(val); /* quad lane 2 = KTC*tanh(g) */            \
    float so = dppf<0xFF>(val); /* quad lane 3 = gate o */                 \
    d = fmaf(sf, d, si * tg);                                              \
    float ec = __builtin_amdgcn_exp2f(d);                                  \
    float rc = __builtin_amdgcn_rcpf(1.0f + ec);                           \
    float h = fmaf(so + so, rc, -so); /* = so*tanh(c), quad-uniform */     \
    r0 = h;                                                                \
    r1 = dppf<0x124>(h); /* row_ror:4  -> h_{(j-1)&3} */                   \
    r2 = dppf<0x128>(h); /* row_ror:8  -> h_{(j-2)&3} */                   \
    r3 = dppf<0x12C>(h); /* row_ror:12 -> h_{(j-3)&3} */                   \
    float ov = fmaf(r3, wl3, fmaf(r2, wl2,                                 \
                    fmaf(r1, wl1, fmaf(r0, wl0, blv))));                   \
    if (sl == (s)) keep = ov;                                              \
  } while (0)

    STEP(0, xa0.x, xa0.y); STEP(1, xa0.z, xa0.w);
    STEP(2, xa1.x, xa1.y); STEP(3, xa1.z, xa1.w);
    STEP(4, xa2.x, xa2.y); STEP(5, xa2.z, xa2.w);
    STEP(6, xa3.x, xa3.y); STEP(7, xa3.z, xa3.w);
#undef STEP

    // Lane l stores out[b, w*8 + l/2, l&1] = flat b*2048 + w*16 + l.
    op[w * 16] = keep;

    xa0 = xb0; xa1 = xb1; xa2 = xb2; xa3 = xb3;
    xb0 = xc0; xb1 = xc1; xb2 = xc2; xb3 = xc3;
  }
}

extern "C" void kernel_launch(void* const* d_in, const int* in_sizes, int n_in,
                              void* d_out, int out_size, void* d_ws, size_t ws_size,
                              hipStream_t stream) {
  const float* x     = (const float*)d_in[0];
  const float* w_ih  = (const float*)d_in[1];
  const float* w_hh  = (const float*)d_in[2];
  const float* b_ih  = (const float*)d_in[3];
  const float* b_hh  = (const float*)d_in[4];
  const float* w_lin = (const float*)d_in[5];
  const float* b_lin = (const float*)d_in[6];
  float* out = (float*)d_out;

  // 8192 groups * 16 lanes = 131072 threads = 2048 waves (2 per SIMD).
  lstm_fused<<<512, 256, 0, stream>>>(x, w_ih, w_hh, b_ih, b_hh, w_lin, b_lin, out);
}

// Round 7
// 123.923 us; speedup vs baseline: 1.2240x; 1.2240x over previous
//
#include <hip/hip_runtime.h>

// LSTM: IN=2, HID=4, OUT=2, B=8192, T=1024.
// 16 lanes/batch, gate-minor: lane = unit*4 + gate; quad j owns unit j.
//   gate broadcast: quad_perm DPP; h gather: row_ror:4/8/12 DPP with
//   (j-m)&3 weight permutation (proven since round 4).
// Cell state pre-scaled d = KTC*c, KTC = -2log2(e); gate weights pre-scaled
// by -log2(e) (g by -2log2(e)).
// THIS ROUND (issue-diet, discriminating issue- vs latency-bound):
//  - v_pk_fma_f32 packs the h-tree (2 pk vs 4 fma) and the projection.
//  - capture r0..r3 at lane's step (cmp + 4 cndmask), project once/window.
//  - 16-step iterations: named per-window store regs (reuse distance
//    ~5000 cy) and x double-buffered one full iteration (16 steps) ahead.
// 8192*16 = 131072 threads = 2048 waves = 2/SIMD on all 1024 SIMDs.

#define T_LEN 1024
#define NITER (T_LEN / 16)

typedef float f32x2 __attribute__((ext_vector_type(2)));

template <int C>
__device__ __forceinline__ float dppf(float v) {
  return __builtin_bit_cast(float,
      __builtin_amdgcn_mov_dpp(__builtin_bit_cast(int, v), C, 0xf, 0xf, true));
}

__device__ __forceinline__ f32x2 pkfma(f32x2 a, f32x2 b, f32x2 c) {
  f32x2 d;
  asm("v_pk_fma_f32 %0, %1, %2, %3" : "=v"(d) : "v"(a), "v"(b), "v"(c));
  return d;
}

__global__ __launch_bounds__(256, 2) void lstm_fused(
    const float* __restrict__ x, const float* __restrict__ w_ih,
    const float* __restrict__ w_hh, const float* __restrict__ b_ih,
    const float* __restrict__ b_hh, const float* __restrict__ w_lin,
    const float* __restrict__ b_lin, float* __restrict__ out) {
  const int tid = blockIdx.x * 256 + threadIdx.x;
  const int b = tid >> 4;        // batch element (one per 16-lane group)
  const int l = tid & 15;        // lane within group
  const int gi = l & 3;          // gate index: 0=i 1=f 2=g 3=o
  const int j = (l >> 2) & 3;    // hidden unit = quad index

  const float L2E = 1.4426950408889634f;
  const float KTC = -2.0f * L2E;  // d = KTC * c

  const int row = gi * 4 + j;     // PyTorch row = gi*4 + j
  const float sc = (gi == 2) ? (-2.0f * L2E) : (-L2E);
  const float wih0 = w_ih[row * 2 + 0] * sc;
  const float wih1 = w_ih[row * 2 + 1] * sc;
  const float bias = (b_ih[row] + b_hh[row]) * sc;
  // r_m (row_ror:4m) = h_{(j-m)&3}
  const int i1 = (j + 3) & 3, i2 = (j + 2) & 3, i3 = (j + 1) & 3;
  // Packed weight pairs for the pk tree: (w0,w2) pairs with (r0,r2) etc.
  f32x2 wh02 = { w_hh[row * 4 + j]  * sc, w_hh[row * 4 + i2] * sc };
  f32x2 wh13 = { w_hh[row * 4 + i1] * sc, w_hh[row * 4 + i3] * sc };
  const float PA = (gi == 2) ? (2.0f * KTC) : 1.0f;
  const float PB = (gi == 2) ? (-KTC) : 0.0f;
  const int o = l & 1;
  f32x2 wp02 = { w_lin[o * 4 + j],  w_lin[o * 4 + i2] };
  f32x2 wp13 = { w_lin[o * 4 + i1], w_lin[o * 4 + i3] };
  f32x2 blvp = { b_lin[o], 0.0f };
  const int sl = l >> 1;  // step-within-window this lane stores

  float d = 0.0f;
  f32x2 R02 = {0.0f, 0.0f};   // (r0, r2) = (h_j, h_{(j-2)&3})
  f32x2 R13 = {0.0f, 0.0f};   // (r1, r3)
  f32x2 axp = {0.0f, 0.0f};   // (ax_s, 0) pk c-operand; .y stays 0

  const float4* xq = (const float4*)(x + (size_t)b * (T_LEN * 2));
  float* op = out + (size_t)b * (T_LEN * 2) + l;

  // x double-buffer: one full 16-step iteration (8 float4) per set.
  float4 s0 = xq[0], s1 = xq[1], s2 = xq[2], s3 = xq[3];
  float4 s4 = xq[4], s5 = xq[5], s6 = xq[6], s7 = xq[7];

  for (int it = 0; it < NITER; ++it) {
    const int nx = (it + 1 < NITER) ? (it + 1) : it;  // clamped tail
    const float4* pn = xq + (size_t)nx * 8;
    float4 n0 = pn[0], n1 = pn[1], n2 = pn[2], n3 = pn[3];
    float4 n4 = pn[4], n5 = pn[5], n6 = pn[6], n7 = pn[7];

    f32x2 kh02, kh13;

#define STEP(s, X0, X1)                                                    \
  do {                                                                     \
    axp.x = fmaf((X1), wih1, fmaf((X0), wih0, bias));                      \
    f32x2 t1 = pkfma(R02, wh02, axp);                                      \
    f32x2 t2 = pkfma(R13, wh13, t1);                                       \
    float a = t2.x + t2.y;                                                 \
    float e = __builtin_amdgcn_exp2f(a);                                   \
    float rr = __builtin_amdgcn_rcpf(1.0f + e);                            \
    float val = fmaf(rr, PA, PB);                                          \
    float si = dppf<0x00>(val);                                            \
    float sf = dppf<0x55>(val);                                            \
    float tg = dppf<0xAA>(val); /* = KTC*tanh(g) */                        \
    float so = dppf<0xFF>(val);                                            \
    d = fmaf(sf, d, si * tg);                                              \
    float ec = __builtin_amdgcn_exp2f(d);                                  \
    float rc = __builtin_amdgcn_rcpf(1.0f + ec);                           \
    float h = fmaf(so + so, rc, -so); /* = so*tanh(c) */                   \
    R02.x = h;                                                             \
    R02.y = dppf<0x128>(h); /* row_ror:8  -> h_{(j-2)&3} */                \
    R13.x = dppf<0x124>(h); /* row_ror:4  -> h_{(j-1)&3} */                \
    R13.y = dppf<0x12C>(h); /* row_ror:12 -> h_{(j-3)&3} */                \
    const bool take = (sl == (s));                                         \
    kh02 = take ? R02 : kh02;                                              \
    kh13 = take ? R13 : kh13;                                              \
  } while (0)

    // ---- window A: steps 0..7 of this iteration ----
    STEP(0, s0.x, s0.y); STEP(1, s0.z, s0.w);
    STEP(2, s1.x, s1.y); STEP(3, s1.z, s1.w);
    STEP(4, s2.x, s2.y); STEP(5, s2.z, s2.w);
    STEP(6, s3.x, s3.y); STEP(7, s3.z, s3.w);
    f32x2 pa = pkfma(kh02, wp02, blvp);
    f32x2 pb = pkfma(kh13, wp13, pa);
    float kva = pb.x + pb.y;          // this window's output (named reg A)
    op[it * 32] = kva;

    // ---- window B: steps 8..15 ----
    STEP(0, s4.x, s4.y); STEP(1, s4.z, s4.w);
    STEP(2, s5.x, s5.y); STEP(3, s5.z, s5.w);
    STEP(4, s6.x, s6.y); STEP(5, s6.z, s6.w);
    STEP(6, s7.x, s7.y); STEP(7, s7.z, s7.w);
    f32x2 pc = pkfma(kh02, wp02, blvp);
    f32x2 pd = pkfma(kh13, wp13, pc);
    float kvb = pd.x + pd.y;          // named reg B (independent of A)
    op[it * 32 + 16] = kvb;
#undef STEP

    s0 = n0; s1 = n1; s2 = n2; s3 = n3;
    s4 = n4; s5 = n5; s6 = n6; s7 = n7;
  }
}

extern "C" void kernel_launch(void* const* d_in, const int* in_sizes, int n_in,
                              void* d_out, int out_size, void* d_ws, size_t ws_size,
                              hipStream_t stream) {
  const float* x     = (const float*)d_in[0];
  const float* w_ih  = (const float*)d_in[1];
  const float* w_hh  = (const float*)d_in[2];
  const float* b_ih  = (const float*)d_in[3];
  const float* b_hh  = (const float*)d_in[4];
  const float* w_lin = (const float*)d_in[5];
  const float* b_lin = (const float*)d_in[6];
  float* out = (float*)d_out;

  // 8192 groups * 16 lanes = 131072 threads = 2048 waves (2 per SIMD).
  lstm_fused<<<512, 256, 0, stream>>>(x, w_ih, w_hh, b_ih, b_hh, w_lin, b_lin, out);
}

// Round 8
// 100.222 us; speedup vs baseline: 1.5134x; 1.2365x over previous
//
#include <hip/hip_runtime.h>

// LSTM: IN=2, HID=4, OUT=2, B=8192, T=1024.
// 8 lanes per batch element: lane l = unit*2 + half; j = l>>1, h = l&1.
//   h=0 computes gates {i,f}; h=1 computes gates {g,o}  (2 exp2+2 rcp each),
//   plus the (per-unit redundant x2) tanh(c) pair: 6 trans/step/lane.
// 65536 threads = 1024 waves = exactly 1 wave/SIMD: per-SIMD issue per step
// drops from 2x116 cy (16-lane version) to ~170 cy; chain (~130cy) hidden.
// Cross-lane, all DPP within the aligned 8-lane group:
//   gate swap within unit: quad_perm 0xB1 (lanes^1)
//   h-gather (r_m = h_{j^m}): r1 = qp 0x4E (lanes^2);
//     r3 = row_half_mirror 0x141 (lanes^7, pair-uniform h absorbs bit0);
//     r2 = qp 0x1B of r3 (^7 then ^3 = lanes^4).
// Weights XOR-permuted by j^m (proven rounds 0-3). Cell state pre-scaled
// d = KTC*c, KTC = -2log2(e); gate weights pre-scaled by -log2(e)
// (g gate by -2log2(e)).
// Output: lane l captures step l's h-vector (4 cndmask/step), projects both
// out columns at window end, stores one float2 -> 64B/group, no masking.

#define T_LEN 1024
#define NW (T_LEN / 8)

template <int C>
__device__ __forceinline__ float dppf(float v) {
  return __builtin_bit_cast(float,
      __builtin_amdgcn_mov_dpp(__builtin_bit_cast(int, v), C, 0xf, 0xf, true));
}

__global__ __launch_bounds__(256, 1) void lstm_fused(
    const float* __restrict__ x, const float* __restrict__ w_ih,
    const float* __restrict__ w_hh, const float* __restrict__ b_ih,
    const float* __restrict__ b_hh, const float* __restrict__ w_lin,
    const float* __restrict__ b_lin, float* __restrict__ out) {
  const int tid = blockIdx.x * 256 + threadIdx.x;
  const int b = tid >> 3;      // batch element (one per 8-lane group)
  const int l = tid & 7;       // lane within group
  const int j = l >> 1;        // hidden unit (0..3)
  const int h = l & 1;         // gate-pair half: 0 -> {i,f}, 1 -> {g,o}

  const float L2E = 1.4426950408889634f;
  const float KTC = -2.0f * L2E;  // d = KTC * c

  const int gA = h ? 2 : 0;    // i or g
  const int gB = h ? 3 : 1;    // f or o
  const float scA = h ? (-2.0f * L2E) : (-L2E);
  const float scB = -L2E;
  const int rowA = gA * 4 + j, rowB = gB * 4 + j;

  const float wihA0 = w_ih[rowA * 2 + 0] * scA;
  const float wihA1 = w_ih[rowA * 2 + 1] * scA;
  const float wihB0 = w_ih[rowB * 2 + 0] * scB;
  const float wihB1 = w_ih[rowB * 2 + 1] * scB;
  const float biasA = (b_ih[rowA] + b_hh[rowA]) * scA;
  const float biasB = (b_ih[rowB] + b_hh[rowB]) * scB;
  float whA[4], whB[4];
#pragma unroll
  for (int m = 0; m < 4; ++m) {
    whA[m] = w_hh[rowA * 4 + (j ^ m)] * scA;   // r_m = h_{j^m}
    whB[m] = w_hh[rowB * 4 + (j ^ m)] * scB;
  }
  // vA post-rcp fixup: h=0 -> si = rr; h=1 -> KTC*tanh(g) = fma(rr,2KTC,-KTC)
  const float PA = h ? (2.0f * KTC) : 1.0f;
  const float PB = h ? (-KTC) : 0.0f;
  // Projection weights: both output columns per lane.
  float wl0[4], wl1[4];
#pragma unroll
  for (int m = 0; m < 4; ++m) {
    wl0[m] = w_lin[0 * 4 + (j ^ m)];
    wl1[m] = w_lin[1 * 4 + (j ^ m)];
  }
  const float bl0 = b_lin[0], bl1 = b_lin[1];
  const bool hb = (h == 1);

  float d = 0.0f;
  float r0 = 0.0f, r1 = 0.0f, r2 = 0.0f, r3 = 0.0f;  // h_{j^m}
  float kh0 = 0.0f, kh1 = 0.0f, kh2 = 0.0f, kh3 = 0.0f;

  // x: all 8 lanes of a group load the same window float4s (HW broadcast).
  const float4* xq = (const float4*)(x + (size_t)b * (T_LEN * 2));
  float2* op2 = (float2*)(out + (size_t)b * (T_LEN * 2));

  float4 xa0 = xq[0], xa1 = xq[1], xa2 = xq[2], xa3 = xq[3];
  float4 xb0 = xq[4], xb1 = xq[5], xb2 = xq[6], xb3 = xq[7];

  for (int w = 0; w < NW; ++w) {
    const int wn = (w + 2 < NW) ? (w + 2) : w;  // clamped tail prefetch
    const float4* pn = xq + (size_t)wn * 4;
    float4 xc0 = pn[0], xc1 = pn[1], xc2 = pn[2], xc3 = pn[3];

#define STEP(s, X0, X1)                                                    \
  do {                                                                     \
    float aA = fmaf((X1), wihA1, fmaf((X0), wihA0, biasA));                \
    aA = fmaf(r0, whA[0], aA); aA = fmaf(r1, whA[1], aA);                  \
    aA = fmaf(r2, whA[2], aA); aA = fmaf(r3, whA[3], aA);                  \
    float aB = fmaf((X1), wihB1, fmaf((X0), wihB0, biasB));                \
    aB = fmaf(r0, whB[0], aB); aB = fmaf(r1, whB[1], aB);                  \
    aB = fmaf(r2, whB[2], aB); aB = fmaf(r3, whB[3], aB);                  \
    float eA = __builtin_amdgcn_exp2f(aA);                                 \
    float eB = __builtin_amdgcn_exp2f(aB);                                 \
    float rrA = __builtin_amdgcn_rcpf(1.0f + eA);                          \
    float rrB = __builtin_amdgcn_rcpf(1.0f + eB);                          \
    float vA = fmaf(rrA, PA, PB); /* si (h=0) | KTC*tanh(g) (h=1) */       \
    float vB = rrB;               /* sf (h=0) | so (h=1) */                \
    float sA = dppf<0xB1>(vA);    /* partner's vA */                       \
    float sB = dppf<0xB1>(vB);    /* partner's vB */                       \
    float si = hb ? sA : vA;                                               \
    float tg = hb ? vA : sA;                                               \
    float sf = hb ? sB : vB;                                               \
    float so = hb ? vB : sB;                                               \
    d = fmaf(sf, d, si * tg);                                              \
    float ec = __builtin_amdgcn_exp2f(d);                                  \
    float rc = __builtin_amdgcn_rcpf(1.0f + ec);                           \
    float hv = fmaf(so + so, rc, -so); /* = so*tanh(c) */                  \
    r0 = hv;                                                               \
    r1 = dppf<0x4E>(hv);   /* lanes^2 -> unit j^1 */                       \
    r3 = dppf<0x141>(hv);  /* row_half_mirror: lanes^7 -> unit j^3 */      \
    r2 = dppf<0x1B>(r3);   /* ^3 after ^7 = lanes^4 -> unit j^2 */         \
    const bool take = (l == (s));                                          \
    kh0 = take ? r0 : kh0; kh1 = take ? r1 : kh1;                          \
    kh2 = take ? r2 : kh2; kh3 = take ? r3 : kh3;                          \
  } while (0)

    STEP(0, xa0.x, xa0.y); STEP(1, xa0.z, xa0.w);
    STEP(2, xa1.x, xa1.y); STEP(3, xa1.z, xa1.w);
    STEP(4, xa2.x, xa2.y); STEP(5, xa2.z, xa2.w);
    STEP(6, xa3.x, xa3.y); STEP(7, xa3.z, xa3.w);
#undef STEP

    // Lane l holds the h-vector of step l; project both outputs, one
    // float2 store -> 64B contiguous per group.
    float o0 = fmaf(kh3, wl0[3], fmaf(kh2, wl0[2],
               fmaf(kh1, wl0[1], fmaf(kh0, wl0[0], bl0))));
    float o1 = fmaf(kh3, wl1[3], fmaf(kh2, wl1[2],
               fmaf(kh1, wl1[1], fmaf(kh0, wl1[0], bl1))));
    float2 ov = {o0, o1};
    op2[w * 8 + l] = ov;

    xa0 = xb0; xa1 = xb1; xa2 = xb2; xa3 = xb3;
    xb0 = xc0; xb1 = xc1; xb2 = xc2; xb3 = xc3;
  }
}

extern "C" void kernel_launch(void* const* d_in, const int* in_sizes, int n_in,
                              void* d_out, int out_size, void* d_ws, size_t ws_size,
                              hipStream_t stream) {
  const float* x     = (const float*)d_in[0];
  const float* w_ih  = (const float*)d_in[1];
  const float* w_hh  = (const float*)d_in[2];
  const float* b_ih  = (const float*)d_in[3];
  const float* b_hh  = (const float*)d_in[4];
  const float* w_lin = (const float*)d_in[5];
  const float* b_lin = (const float*)d_in[6];
  float* out = (float*)d_out;

  // 8192 groups * 8 lanes = 65536 threads = 1024 waves = 1 per SIMD.
  lstm_fused<<<256, 256, 0, stream>>>(x, w_ih, w_hh, b_ih, b_hh, w_lin, b_lin, out);
}